// Round 4
// baseline (210.220 us; speedup 1.0000x reference)
//
#include <hip/hip_runtime.h>
#include <math.h>

// MoE router: x[16384,2048] fp32, W[8,2048] fp32 -> (top2 idx, top2 gates, logits)
// Memory-bound: 134 MB read-once. v4: v1's proven balance (8 tokens/wave, 1:1 W:x
// loads, 8KB x in flight/iter) + D split across wave pairs -> 4096 waves (4/SIMD),
// butterfly reduce-scatter epilogue + 1KB LDS pair-combine (no 64KB transpose).

constexpr int D      = 2048;
constexpr int E      = 8;
constexpr int T      = 8;       // tokens per wave pair
constexpr int TOKENS = 16384;

typedef float f32x4 __attribute__((ext_vector_type(4)));

__device__ __forceinline__ bool better(float va, int ia, float vb, int ib) {
    // jax.lax.top_k tie rule: larger value wins; equal values -> smaller index
    return (va > vb) || (va == vb && ia < ib);
}

__global__ __launch_bounds__(256, 4)
void moe_router_kernel(const float* __restrict__ x,
                       const float* __restrict__ w,
                       float* __restrict__ out)
{
    const int lane = threadIdx.x & 63;
    const int wid  = threadIdx.x >> 6;   // 0..3
    const int pair = wid >> 1;           // 0..1: token-group within block
    const int half = wid & 1;            // 0..1: which half of D this wave owns
    const int tok0 = (blockIdx.x * 2 + pair) * T;

    const float* xbase = x + (size_t)tok0 * D + half * (D / 2) + lane * 4;
    const float* wbase = w + half * (D / 2) + lane * 4;

    float acc[T * E];
#pragma unroll
    for (int i = 0; i < T * E; ++i) acc[i] = 0.0f;

    // 4 iters cover this wave's 1024 dims. Per iter: 8 x-loads (8KB HBM stream,
    // issued back-to-back) + 8 W-loads (L1/L2) + 256 FMAs. 1:1 W:x like v1.
#pragma unroll 1
    for (int it = 0; it < D / 512; ++it) {
        const int d = it * 256;
        f32x4 xv[T];
#pragma unroll
        for (int t = 0; t < T; ++t)
            xv[t] = *reinterpret_cast<const f32x4*>(xbase + (size_t)t * D + d);
#pragma unroll
        for (int e = 0; e < E; ++e) {
            const f32x4 wv = *reinterpret_cast<const f32x4*>(wbase + e * D + d);
#pragma unroll
            for (int t = 0; t < T; ++t) {
                float a = acc[t * E + e];
                a = fmaf(xv[t].x, wv.x, a);
                a = fmaf(xv[t].y, wv.y, a);
                a = fmaf(xv[t].z, wv.z, a);
                a = fmaf(xv[t].w, wv.w, a);
                acc[t * E + e] = a;
            }
        }
    }

    // ---- Butterfly reduce-scatter: 64 (token,expert) sums across 64 lanes.
    // After all stages, lane p holds this wave's half-D sum for p=(t<<3)|e.
    const bool s32 = (lane & 32) != 0;
    float r32[32];
#pragma unroll
    for (int i = 0; i < 32; ++i) {
        const float keep = s32 ? acc[i + 32] : acc[i];
        const float send = s32 ? acc[i]      : acc[i + 32];
        r32[i] = keep + __shfl_xor(send, 32, 64);  // p = (lane&32)+i
    }
    const bool s16 = (lane & 16) != 0;
    float r16[16];
#pragma unroll
    for (int i = 0; i < 16; ++i) {
        const float keep = s16 ? r32[i + 16] : r32[i];
        const float send = s16 ? r32[i]      : r32[i + 16];
        r16[i] = keep + __shfl_xor(send, 16, 64);  // p = (lane&48)+i
    }
    const bool s8 = (lane & 8) != 0;
    float r8[8];
#pragma unroll
    for (int i = 0; i < 8; ++i) {
        const float keep = s8 ? r16[i + 8] : r16[i];
        const float send = s8 ? r16[i]     : r16[i + 8];
        r8[i] = keep + __shfl_xor(send, 8, 64);    // p = (lane&56)+i
    }
    const bool s4 = (lane & 4) != 0;
    float r4[4];
#pragma unroll
    for (int i = 0; i < 4; ++i) {
        const float keep = s4 ? r8[i + 4] : r8[i];
        const float send = s4 ? r8[i]     : r8[i + 4];
        r4[i] = keep + __shfl_xor(send, 4, 64);    // p = (lane&60)+i
    }
    const bool s2 = (lane & 2) != 0;
    float r2[2];
#pragma unroll
    for (int i = 0; i < 2; ++i) {
        const float keep = s2 ? r4[i + 2] : r4[i];
        const float send = s2 ? r4[i]     : r4[i + 2];
        r2[i] = keep + __shfl_xor(send, 2, 64);    // p = (lane&62)+i
    }
    const bool s1 = (lane & 1) != 0;
    float partial;
    {
        const float keep = s1 ? r2[1] : r2[0];
        const float send = s1 ? r2[0] : r2[1];
        partial = keep + __shfl_xor(send, 1, 64);  // p = lane
    }

    // ---- Combine the two D-halves of this pair via 1KB LDS.
    __shared__ float part[2][2][64];
    part[pair][half][lane] = partial;
    __syncthreads();
    const float logit = part[pair][0][lane] + part[pair][1][lane];

    const int e     = lane & 7;
    const int t     = lane >> 3;
    const int token = tok0 + t;

    float* out_idx    = out;                 // [TOKENS][2] (indices as fp32)
    float* out_gate   = out + TOKENS * 2;    // [TOKENS][2]
    float* out_logits = out + TOKENS * 4;    // [TOKENS][8]

    // Wave 0 of the pair writes all 64 logits: one coalesced 256B store.
    if (half == 0) out_logits[(size_t)tok0 * E + lane] = logit;

    // Top-2 across the 8 lanes of each octet (xor masks 1,2,4 stay in-octet).
    float v1 = logit, v2 = -INFINITY;
    int   i1 = e,     i2 = E;
#pragma unroll
    for (int m = 1; m <= 4; m <<= 1) {
        float ov1 = __shfl_xor(v1, m, 64);
        int   oi1 = __shfl_xor(i1, m, 64);
        float ov2 = __shfl_xor(v2, m, 64);
        int   oi2 = __shfl_xor(i2, m, 64);
        float nv1, nv2; int ni1, ni2;
        if (better(v1, i1, ov1, oi1)) {
            nv1 = v1; ni1 = i1;
            if (better(v2, i2, ov1, oi1)) { nv2 = v2;  ni2 = i2;  }
            else                          { nv2 = ov1; ni2 = oi1; }
        } else {
            nv1 = ov1; ni1 = oi1;
            if (better(ov2, oi2, v1, i1)) { nv2 = ov2; ni2 = oi2; }
            else                          { nv2 = v1;  ni2 = i1;  }
        }
        v1 = nv1; i1 = ni1; v2 = nv2; i2 = ni2;
    }

    // softmax over the 2 selected logits: [1, e^(v2-v1)] / (1 + e^(v2-v1))
    if (half == 0 && e < 2) {
        const float ed  = expf(v2 - v1);          // v2 <= v1, so ed in (0,1]
        const float inv = 1.0f / (1.0f + ed);
        const float g   = (e == 0) ? inv : ed * inv;
        out_idx [token * 2 + e] = (float)((e == 0) ? i1 : i2);
        out_gate[token * 2 + e] = g;
    }
}

extern "C" void kernel_launch(void* const* d_in, const int* in_sizes, int n_in,
                              void* d_out, int out_size, void* d_ws, size_t ws_size,
                              hipStream_t stream) {
    const float* x = (const float*)d_in[0];
    const float* w = (const float*)d_in[1];
    float* out = (float*)d_out;
    // 16384 tokens / (2 pairs * 8 tokens) = 1024 blocks, 256 threads each.
    hipLaunchKernelGGL(moe_router_kernel, dim3(1024), dim3(256), 0, stream,
                       x, w, out);
}

// Round 5
// 189.076 us; speedup vs baseline: 1.1118x; 1.1118x over previous
//
#include <hip/hip_runtime.h>
#include <math.h>

// MoE router: x[16384,2048] fp32, W[8,2048] fp32 -> (top2 idx, top2 gates, logits)
// Memory-bound: 134 MB read-once. v5 = v1's proven per-wave structure (8 tokens/
// wave, 1:1 W:x loads, full-unroll K-loop, rotated LDS transpose) decomposed into
// 1-wave blocks: no inter-wave barrier coupling, independent retirement, 16KB LDS.

constexpr int D      = 2048;
constexpr int E      = 8;
constexpr int T      = 8;      // tokens per wave
constexpr int TOKENS = 16384;

typedef float f32x4 __attribute__((ext_vector_type(4)));

__device__ __forceinline__ bool better(float va, int ia, float vb, int ib) {
    // jax.lax.top_k tie rule: larger value wins; equal values -> smaller index
    return (va > vb) || (va == vb && ia < ib);
}

__global__ __launch_bounds__(64, 2)
void moe_router_kernel(const float* __restrict__ x,
                       const float* __restrict__ w,
                       float* __restrict__ out)
{
    // 64 pairs x 64 lanes, rotated columns for bank-conflict-free scatter+gather.
    __shared__ float scr[64][64];   // 16 KiB

    const int lane = threadIdx.x & 63;
    const int tok0 = blockIdx.x * T;

    float acc[T * E];
#pragma unroll
    for (int i = 0; i < T * E; ++i) acc[i] = 0.0f;

    // K loop: 8 iterations cover D=2048. Lane l handles dims it*256 + l*4 .. +3.
    // Per iter: 8 x-loads (8KB HBM stream, back-to-back) + 8 W-loads (L1/L2
    // resident) + 256 FMAs. Full unroll lets the compiler pipeline across iters.
#pragma unroll
    for (int it = 0; it < D / 256; ++it) {
        const int d = it * 256 + lane * 4;
        f32x4 wv[E];
#pragma unroll
        for (int e = 0; e < E; ++e)
            wv[e] = *reinterpret_cast<const f32x4*>(w + e * D + d);
        f32x4 xv[T];
#pragma unroll
        for (int t = 0; t < T; ++t)
            xv[t] = *reinterpret_cast<const f32x4*>(x + (size_t)(tok0 + t) * D + d);
#pragma unroll
        for (int t = 0; t < T; ++t) {
#pragma unroll
            for (int e = 0; e < E; ++e) {
                float a = acc[t * E + e];
                a = fmaf(xv[t].x, wv[e].x, a);
                a = fmaf(xv[t].y, wv[e].y, a);
                a = fmaf(xv[t].z, wv[e].z, a);
                a = fmaf(xv[t].w, wv[e].w, a);
                acc[t * E + e] = a;
            }
        }
    }

    // Scatter partials: row p = (token t = p>>3, expert e = p&7), rotated column.
#pragma unroll
    for (int p = 0; p < 64; ++p)
        scr[p][(lane + p) & 63] = acc[p];

    __syncthreads();   // single-wave block: compiles to a cheap wait + barrier

    // Lane l reduces row l (its pair) over all 64 source lanes, rotated reads.
    float s0 = 0.f, s1 = 0.f, s2 = 0.f, s3 = 0.f;
#pragma unroll
    for (int j = 0; j < 64; j += 4) {
        s0 += scr[lane][(lane + j + 0) & 63];
        s1 += scr[lane][(lane + j + 1) & 63];
        s2 += scr[lane][(lane + j + 2) & 63];
        s3 += scr[lane][(lane + j + 3) & 63];
    }
    const float logit = (s0 + s1) + (s2 + s3);

    const int t     = lane >> 3;
    const int e     = lane & 7;
    const int token = tok0 + t;

    float* out_idx    = out;                 // [TOKENS][2] (indices stored as fp32)
    float* out_gate   = out + TOKENS * 2;    // [TOKENS][2]
    float* out_logits = out + TOKENS * 4;    // [TOKENS][8]

    // logits store: address = tok0*8 + lane -> one coalesced 256B store per wave
    out_logits[(size_t)token * E + e] = logit;

    // Top-2 across the 8 lanes of this token (xor masks 1,2,4 stay in-group).
    float v1 = logit, v2 = -INFINITY;
    int   i1 = e,     i2 = E;
#pragma unroll
    for (int m = 1; m <= 4; m <<= 1) {
        float ov1 = __shfl_xor(v1, m, 64);
        int   oi1 = __shfl_xor(i1, m, 64);
        float ov2 = __shfl_xor(v2, m, 64);
        int   oi2 = __shfl_xor(i2, m, 64);
        float nv1, nv2; int ni1, ni2;
        if (better(v1, i1, ov1, oi1)) {
            nv1 = v1; ni1 = i1;
            if (better(v2, i2, ov1, oi1)) { nv2 = v2;  ni2 = i2;  }
            else                          { nv2 = ov1; ni2 = oi1; }
        } else {
            nv1 = ov1; ni1 = oi1;
            if (better(ov2, oi2, v1, i1)) { nv2 = ov2; ni2 = oi2; }
            else                          { nv2 = v1;  ni2 = i1;  }
        }
        v1 = nv1; i1 = ni1; v2 = nv2; i2 = ni2;
    }

    // softmax over the 2 selected logits: [1, e^(v2-v1)] / (1 + e^(v2-v1))
    if (e < 2) {
        const float ed  = expf(v2 - v1);          // v2 <= v1, so ed in (0,1]
        const float inv = 1.0f / (1.0f + ed);
        const float g   = (e == 0) ? inv : ed * inv;
        out_idx [token * 2 + e] = (float)((e == 0) ? i1 : i2);
        out_gate[token * 2 + e] = g;
    }
}

extern "C" void kernel_launch(void* const* d_in, const int* in_sizes, int n_in,
                              void* d_out, int out_size, void* d_ws, size_t ws_size,
                              hipStream_t stream) {
    const float* x = (const float*)d_in[0];
    const float* w = (const float*)d_in[1];
    float* out = (float*)d_out;
    // 16384 tokens / 8 tokens-per-wave = 2048 one-wave blocks, 64 threads each.
    hipLaunchKernelGGL(moe_router_kernel, dim3(2048), dim3(64), 0, stream,
                       x, w, out);
}

// Round 6
// 185.484 us; speedup vs baseline: 1.1334x; 1.0194x over previous
//
#include <hip/hip_runtime.h>
#include <math.h>

// MoE router: x[16384,2048] fp32, W[8,2048] fp32 -> (top2 idx, top2 gates, logits)
// Memory-bound: 134 MB read-once. v6 = v5 (1-wave blocks, 8 tokens/wave, 1:1 W:x,
// rotated LDS transpose) + explicit 1-deep x-load software pipeline (next iter's
// 8KB in flight under this iter's 512 FMA-cycles) + nontemporal x loads.

constexpr int D      = 2048;
constexpr int E      = 8;
constexpr int T      = 8;      // tokens per wave
constexpr int TOKENS = 16384;

typedef float f32x4 __attribute__((ext_vector_type(4)));

__device__ __forceinline__ bool better(float va, int ia, float vb, int ib) {
    // jax.lax.top_k tie rule: larger value wins; equal values -> smaller index
    return (va > vb) || (va == vb && ia < ib);
}

__global__ __launch_bounds__(64, 2)
void moe_router_kernel(const float* __restrict__ x,
                       const float* __restrict__ w,
                       float* __restrict__ out)
{
    // 64 pairs x 64 lanes, rotated columns for bank-conflict-free scatter+gather.
    __shared__ float scr[64][64];   // 16 KiB

    const int lane = threadIdx.x & 63;
    const int tok0 = blockIdx.x * T;

    const float* xbase = x + (size_t)tok0 * D + lane * 4;
    const float* wbase = w + lane * 4;

    float acc[T * E];
#pragma unroll
    for (int i = 0; i < T * E; ++i) acc[i] = 0.0f;

    // Software pipeline: xv_cur holds iter it's 8KB; xv_nxt prefetches it+1's
    // while the 256 FMAs of iter it run. Swap is register renaming (full unroll).
    f32x4 xv_cur[T], xv_nxt[T];
#pragma unroll
    for (int t = 0; t < T; ++t)
        xv_cur[t] = __builtin_nontemporal_load(
            reinterpret_cast<const f32x4*>(xbase + (size_t)t * D));

#pragma unroll
    for (int it = 0; it < D / 256; ++it) {
        const int d = it * 256;
        if (it < D / 256 - 1) {
#pragma unroll
            for (int t = 0; t < T; ++t)
                xv_nxt[t] = __builtin_nontemporal_load(
                    reinterpret_cast<const f32x4*>(xbase + (size_t)t * D + d + 256));
        }
        f32x4 wv[E];
#pragma unroll
        for (int e = 0; e < E; ++e)
            wv[e] = *reinterpret_cast<const f32x4*>(wbase + e * D + d);
#pragma unroll
        for (int t = 0; t < T; ++t) {
#pragma unroll
            for (int e = 0; e < E; ++e) {
                float a = acc[t * E + e];
                a = fmaf(xv_cur[t].x, wv[e].x, a);
                a = fmaf(xv_cur[t].y, wv[e].y, a);
                a = fmaf(xv_cur[t].z, wv[e].z, a);
                a = fmaf(xv_cur[t].w, wv[e].w, a);
                acc[t * E + e] = a;
            }
        }
#pragma unroll
        for (int t = 0; t < T; ++t) xv_cur[t] = xv_nxt[t];
    }

    // Scatter partials: row p = (token t = p>>3, expert e = p&7), rotated column.
#pragma unroll
    for (int p = 0; p < 64; ++p)
        scr[p][(lane + p) & 63] = acc[p];

    __syncthreads();   // single-wave block: cheap

    // Lane l reduces row l (its pair) over all 64 source lanes, rotated reads.
    float s0 = 0.f, s1 = 0.f, s2 = 0.f, s3 = 0.f;
#pragma unroll
    for (int j = 0; j < 64; j += 4) {
        s0 += scr[lane][(lane + j + 0) & 63];
        s1 += scr[lane][(lane + j + 1) & 63];
        s2 += scr[lane][(lane + j + 2) & 63];
        s3 += scr[lane][(lane + j + 3) & 63];
    }
    const float logit = (s0 + s1) + (s2 + s3);

    const int t     = lane >> 3;
    const int e     = lane & 7;
    const int token = tok0 + t;

    float* out_idx    = out;                 // [TOKENS][2] (indices stored as fp32)
    float* out_gate   = out + TOKENS * 2;    // [TOKENS][2]
    float* out_logits = out + TOKENS * 4;    // [TOKENS][8]

    // logits store: address = tok0*8 + lane -> one coalesced 256B store per wave
    out_logits[(size_t)token * E + e] = logit;

    // Top-2 across the 8 lanes of this token (xor masks 1,2,4 stay in-group).
    float v1 = logit, v2 = -INFINITY;
    int   i1 = e,     i2 = E;
#pragma unroll
    for (int m = 1; m <= 4; m <<= 1) {
        float ov1 = __shfl_xor(v1, m, 64);
        int   oi1 = __shfl_xor(i1, m, 64);
        float ov2 = __shfl_xor(v2, m, 64);
        int   oi2 = __shfl_xor(i2, m, 64);
        float nv1, nv2; int ni1, ni2;
        if (better(v1, i1, ov1, oi1)) {
            nv1 = v1; ni1 = i1;
            if (better(v2, i2, ov1, oi1)) { nv2 = v2;  ni2 = i2;  }
            else                          { nv2 = ov1; ni2 = oi1; }
        } else {
            nv1 = ov1; ni1 = oi1;
            if (better(ov2, oi2, v1, i1)) { nv2 = ov2; ni2 = oi2; }
            else                          { nv2 = v1;  ni2 = i1;  }
        }
        v1 = nv1; i1 = ni1; v2 = nv2; i2 = ni2;
    }

    // softmax over the 2 selected logits: [1, e^(v2-v1)] / (1 + e^(v2-v1))
    if (e < 2) {
        const float ed  = expf(v2 - v1);          // v2 <= v1, so ed in (0,1]
        const float inv = 1.0f / (1.0f + ed);
        const float g   = (e == 0) ? inv : ed * inv;
        out_idx [token * 2 + e] = (float)((e == 0) ? i1 : i2);
        out_gate[token * 2 + e] = g;
    }
}

extern "C" void kernel_launch(void* const* d_in, const int* in_sizes, int n_in,
                              void* d_out, int out_size, void* d_ws, size_t ws_size,
                              hipStream_t stream) {
    const float* x = (const float*)d_in[0];
    const float* w = (const float*)d_in[1];
    float* out = (float*)d_out;
    // 16384 tokens / 8 tokens-per-wave = 2048 one-wave blocks, 64 threads each.
    hipLaunchKernelGGL(moe_router_kernel, dim3(2048), dim3(64), 0, stream,
                       x, w, out);
}

// Round 7
// 184.534 us; speedup vs baseline: 1.1392x; 1.0052x over previous
//
#include <hip/hip_runtime.h>
#include <math.h>

// MoE router: x[16384,2048] fp32, W[8,2048] fp32 -> (top2 idx, top2 gates, logits)
// Memory-bound: 134 MB read-once. v7 = v6 + in-order-vmcnt-correct schedule:
// per iter issue [W(it+1) then x(it+2)]; FMA(it) waits only on ops >=1/2 iters
// old (W: 512cy>200 L2-lat, x: 1024cy>900 HBM-lat) -> steady-state stall ~0.
// Regs: acc64 + 3x32 xv + 2x32 wv ~ 240 < 256 @ launch_bounds(64,2).

constexpr int D      = 2048;
constexpr int E      = 8;
constexpr int T      = 8;      // tokens per wave
constexpr int ITERS  = D / 256;
constexpr int TOKENS = 16384;

typedef float f32x4 __attribute__((ext_vector_type(4)));

__device__ __forceinline__ bool better(float va, int ia, float vb, int ib) {
    // jax.lax.top_k tie rule: larger value wins; equal values -> smaller index
    return (va > vb) || (va == vb && ia < ib);
}

__global__ __launch_bounds__(64, 2)
void moe_router_kernel(const float* __restrict__ x,
                       const float* __restrict__ w,
                       float* __restrict__ out)
{
    // 64 pairs x 64 lanes, rotated columns for bank-conflict-free scatter+gather.
    __shared__ float scr[64][64];   // 16 KiB

    const int lane = threadIdx.x & 63;
    const int tok0 = blockIdx.x * T;

    const float* xbase = x + (size_t)tok0 * D + lane * 4;
    const float* wbase = w + lane * 4;

    float acc[T * E];
#pragma unroll
    for (int i = 0; i < T * E; ++i) acc[i] = 0.0f;

    f32x4 wv_cur[E], wv_nxt[E];
    f32x4 xv_cur[T], xv_n1[T], xv_n2[T];

    // Prologue: W(0), x(0), x(1) — in this order so waits on W never force
    // younger x-prefetches (vmcnt drains in issue order).
#pragma unroll
    for (int e = 0; e < E; ++e)
        wv_cur[e] = *reinterpret_cast<const f32x4*>(wbase + e * D);
#pragma unroll
    for (int t = 0; t < T; ++t)
        xv_cur[t] = __builtin_nontemporal_load(
            reinterpret_cast<const f32x4*>(xbase + (size_t)t * D));
#pragma unroll
    for (int t = 0; t < T; ++t)
        xv_n1[t] = __builtin_nontemporal_load(
            reinterpret_cast<const f32x4*>(xbase + (size_t)t * D + 256));

#pragma unroll
    for (int it = 0; it < ITERS; ++it) {
        // Issue next-gen loads BEFORE this iter's FMAs: W first, then x.
        if (it + 1 < ITERS) {
            const int dw = (it + 1) * 256;
#pragma unroll
            for (int e = 0; e < E; ++e)
                wv_nxt[e] = *reinterpret_cast<const f32x4*>(wbase + e * D + dw);
        }
        if (it + 2 < ITERS) {
            const int dx = (it + 2) * 256;
#pragma unroll
            for (int t = 0; t < T; ++t)
                xv_n2[t] = __builtin_nontemporal_load(
                    reinterpret_cast<const f32x4*>(xbase + (size_t)t * D + dx));
        }

        // 256 FMAs on wv_cur/xv_cur (both issued >=1/2 iters ago).
#pragma unroll
        for (int t = 0; t < T; ++t) {
#pragma unroll
            for (int e = 0; e < E; ++e) {
                float a = acc[t * E + e];
                a = fmaf(xv_cur[t].x, wv_cur[e].x, a);
                a = fmaf(xv_cur[t].y, wv_cur[e].y, a);
                a = fmaf(xv_cur[t].z, wv_cur[e].z, a);
                a = fmaf(xv_cur[t].w, wv_cur[e].w, a);
                acc[t * E + e] = a;
            }
        }

        // Rotate pipeline registers (renames under full unroll).
        if (it + 1 < ITERS) {
#pragma unroll
            for (int e = 0; e < E; ++e) wv_cur[e] = wv_nxt[e];
#pragma unroll
            for (int t = 0; t < T; ++t) xv_cur[t] = xv_n1[t];
        }
        if (it + 2 < ITERS) {
#pragma unroll
            for (int t = 0; t < T; ++t) xv_n1[t] = xv_n2[t];
        }
    }

    // Scatter partials: row p = (token t = p>>3, expert e = p&7), rotated column.
#pragma unroll
    for (int p = 0; p < 64; ++p)
        scr[p][(lane + p) & 63] = acc[p];

    __syncthreads();   // single-wave block: cheap

    // Lane l reduces row l (its pair) over all 64 source lanes, rotated reads.
    float s0 = 0.f, s1 = 0.f, s2 = 0.f, s3 = 0.f;
#pragma unroll
    for (int j = 0; j < 64; j += 4) {
        s0 += scr[lane][(lane + j + 0) & 63];
        s1 += scr[lane][(lane + j + 1) & 63];
        s2 += scr[lane][(lane + j + 2) & 63];
        s3 += scr[lane][(lane + j + 3) & 63];
    }
    const float logit = (s0 + s1) + (s2 + s3);

    const int t     = lane >> 3;
    const int e     = lane & 7;
    const int token = tok0 + t;

    float* out_idx    = out;                 // [TOKENS][2] (indices stored as fp32)
    float* out_gate   = out + TOKENS * 2;    // [TOKENS][2]
    float* out_logits = out + TOKENS * 4;    // [TOKENS][8]

    // logits store: address = tok0*8 + lane -> one coalesced 256B store per wave
    out_logits[(size_t)token * E + e] = logit;

    // Top-2 across the 8 lanes of this token (xor masks 1,2,4 stay in-group).
    float v1 = logit, v2 = -INFINITY;
    int   i1 = e,     i2 = E;
#pragma unroll
    for (int m = 1; m <= 4; m <<= 1) {
        float ov1 = __shfl_xor(v1, m, 64);
        int   oi1 = __shfl_xor(i1, m, 64);
        float ov2 = __shfl_xor(v2, m, 64);
        int   oi2 = __shfl_xor(i2, m, 64);
        float nv1, nv2; int ni1, ni2;
        if (better(v1, i1, ov1, oi1)) {
            nv1 = v1; ni1 = i1;
            if (better(v2, i2, ov1, oi1)) { nv2 = v2;  ni2 = i2;  }
            else                          { nv2 = ov1; ni2 = oi1; }
        } else {
            nv1 = ov1; ni1 = oi1;
            if (better(ov2, oi2, v1, i1)) { nv2 = ov2; ni2 = oi2; }
            else                          { nv2 = v1;  ni2 = i1;  }
        }
        v1 = nv1; i1 = ni1; v2 = nv2; i2 = ni2;
    }

    // softmax over the 2 selected logits: [1, e^(v2-v1)] / (1 + e^(v2-v1))
    if (e < 2) {
        const float ed  = expf(v2 - v1);          // v2 <= v1, so ed in (0,1]
        const float inv = 1.0f / (1.0f + ed);
        const float g   = (e == 0) ? inv : ed * inv;
        out_idx [token * 2 + e] = (float)((e == 0) ? i1 : i2);
        out_gate[token * 2 + e] = g;
    }
}

extern "C" void kernel_launch(void* const* d_in, const int* in_sizes, int n_in,
                              void* d_out, int out_size, void* d_ws, size_t ws_size,
                              hipStream_t stream) {
    const float* x = (const float*)d_in[0];
    const float* w = (const float*)d_in[1];
    float* out = (float*)d_out;
    // 16384 tokens / 8 tokens-per-wave = 2048 one-wave blocks, 64 threads each.
    hipLaunchKernelGGL(moe_router_kernel, dim3(2048), dim3(64), 0, stream,
                       x, w, out);
}